// Round 4
// baseline (121.875 us; speedup 1.0000x reference)
//
#include <hip/hip_runtime.h>

#define TOKENS 8192
#define EXPERTS 64
#define HIDDEN 4096
#define SPLIT 8
#define KSEG (HIDDEN / SPLIT)    // 512 k per block
#define CHUNK 64                 // k staged per LDS pass
#define NCH (KSEG / CHUNK)       // 8 chunks
#define PAD 68                   // row stride in floats (16B-aligned, bank-clean)

// ---------------------------------------------------------------------------
// Kernel A: transpose weight [64][4096] -> wT [4096][64], LDS-tiled.
// ---------------------------------------------------------------------------
__global__ void transpose_w_kernel(const float* __restrict__ w,
                                   float* __restrict__ wT) {
    __shared__ float tile[64][65];
    const int tid = threadIdx.x;           // 256 threads
    const int kb = blockIdx.x * 64;        // 64 k per block, 64 blocks
#pragma unroll
    for (int p = 0; p < 16; ++p) {
        const int e = p * 4 + (tid >> 6);
        const int kk = tid & 63;
        tile[e][kk] = w[(size_t)e * HIDDEN + kb + kk];
    }
    __syncthreads();
#pragma unroll
    for (int q = 0; q < 16; ++q) {
        const int kr = q * 4 + (tid >> 6);
        const int ee = tid & 63;
        wT[(size_t)(kb + kr) * 64 + ee] = tile[ee][kr];
    }
}

// ---------------------------------------------------------------------------
// Kernel B: partial logits, double-buffered reg-staged pipeline.
// Grid = 128 token-groups x SPLIT k-segments, block = 256 (4 waves).
// lane = token. Wave w owns experts [w*16, w*16+16); acc[16] register-resident.
// Per chunk: ds_write prefetched regs -> buf[c&1]; ONE barrier; issue next
// chunk's global loads (wait deferred to next ds_write, hidden under 2048
// cycles of fmac); compute. Weights via wave-uniform s_load from wT.
// ---------------------------------------------------------------------------
__global__ __launch_bounds__(256, 4)
void logits_partial_kernel(const float* __restrict__ x,
                           const float* __restrict__ wT,
                           float* __restrict__ part) {
    __shared__ float smem[2][64 * PAD];    // 2 x 17408 B
    const int tid = threadIdx.x;
    const int lane = tid & 63;
    const int e0 = __builtin_amdgcn_readfirstlane((tid >> 6) * 16);
    const int g = blockIdx.x / SPLIT;      // token group (0..127)
    const int s = blockIdx.x % SPLIT;      // k segment (0..7)
    const int t0 = g * 64;
    const int k0 = s * KSEG;

    float acc[16];
#pragma unroll
    for (int j = 0; j < 16; ++j) acc[j] = 0.0f;

    const int rowb = tid >> 4;             // 0..15
    const int kk4 = (tid & 15) * 4;        // float4 column within 64-k chunk
    const float* __restrict__ xbase = x + (size_t)t0 * HIDDEN + k0;

    // prologue: prefetch chunk 0 into registers
    float4 r[4];
#pragma unroll
    for (int p = 0; p < 4; ++p) {
        r[p] = *reinterpret_cast<const float4*>(
            xbase + (size_t)(p * 16 + rowb) * HIDDEN + kk4);
    }

    for (int c = 0; c < NCH; ++c) {
        float* buf = smem[c & 1];
        // write prefetched chunk to LDS (vmcnt wait folded in by dependency)
#pragma unroll
        for (int p = 0; p < 4; ++p) {
            *reinterpret_cast<float4*>(&buf[(p * 16 + rowb) * PAD + kk4]) = r[p];
        }
        __syncthreads();
        // issue next chunk's loads now; consumed by next iteration's ds_write
        if (c + 1 < NCH) {
#pragma unroll
            for (int p = 0; p < 4; ++p) {
                r[p] = *reinterpret_cast<const float4*>(
                    xbase + (size_t)(p * 16 + rowb) * HIDDEN
                          + (c + 1) * CHUNK + kk4);
            }
        }
        // compute chunk c: 16 iters x (1 ds_read_b128 + 64 fmac)
        const float* __restrict__ wbase = wT + (size_t)(k0 + c * CHUNK) * 64 + e0;
#pragma unroll 4
        for (int kk = 0; kk < CHUNK; kk += 4) {
            const float4 xv = *reinterpret_cast<const float4*>(
                &buf[lane * PAD + kk]);
            const float* __restrict__ wrow = wbase + (size_t)kk * 64;
#pragma unroll
            for (int j = 0; j < 16; ++j)
                acc[j] = fmaf(wrow[j], xv.x, acc[j]);
#pragma unroll
            for (int j = 0; j < 16; ++j)
                acc[j] = fmaf(wrow[64 + j], xv.y, acc[j]);
#pragma unroll
            for (int j = 0; j < 16; ++j)
                acc[j] = fmaf(wrow[128 + j], xv.z, acc[j]);
#pragma unroll
            for (int j = 0; j < 16; ++j)
                acc[j] = fmaf(wrow[192 + j], xv.w, acc[j]);
        }
        __syncthreads();
    }

    // write partial: part[s][t0+lane][e0..e0+15], 4x float4 per lane
    float* dst = part + ((size_t)s * TOKENS + t0 + lane) * EXPERTS + e0;
#pragma unroll
    for (int j = 0; j < 16; j += 4) {
        float4 v = make_float4(acc[j], acc[j + 1], acc[j + 2], acc[j + 3]);
        *reinterpret_cast<float4*>(dst + j) = v;
    }
}

// ---------------------------------------------------------------------------
// Kernel C: reduce partials -> softmax -> top-8 -> probs + routing map.
// One wave per token; lane = expert. Tie-break: lower index (lax.top_k).
// ---------------------------------------------------------------------------
__global__ void reduce_topk_kernel(const float* __restrict__ part,
                                   float* __restrict__ out) {
    const int wid = threadIdx.x >> 6;
    const int lane = threadIdx.x & 63;
    const int t = blockIdx.x * 4 + wid;

    float logit = 0.0f;
#pragma unroll
    for (int s = 0; s < SPLIT; ++s) {
        logit += part[((size_t)s * TOKENS + t) * EXPERTS + lane];
    }

    // softmax over the 64 lanes
    float m = logit;
#pragma unroll
    for (int off = 32; off >= 1; off >>= 1) m = fmaxf(m, __shfl_xor(m, off, 64));
    const float ex = __expf(logit - m);
    float sum = ex;
#pragma unroll
    for (int off = 32; off >= 1; off >>= 1) sum += __shfl_xor(sum, off, 64);
    const float score = ex / sum;

    // iterative top-8: argmax with (value desc, index asc) tie-break
    float v = score;
    bool sel = false;
#pragma unroll
    for (int it = 0; it < 8; ++it) {
        float bv = v;
        int bi = lane;
#pragma unroll
        for (int off = 32; off >= 1; off >>= 1) {
            const float ov = __shfl_xor(bv, off, 64);
            const int oi = __shfl_xor(bi, off, 64);
            if (ov > bv || (ov == bv && oi < bi)) { bv = ov; bi = oi; }
        }
        if (lane == bi) { sel = true; v = -1.0f; }  // scores are > 0
    }

    out[(size_t)t * EXPERTS + lane] = sel ? score : 0.0f;
    out[(size_t)TOKENS * EXPERTS + (size_t)t * EXPERTS + lane] = sel ? 1.0f : 0.0f;
}

// ---------------------------------------------------------------------------
extern "C" void kernel_launch(void* const* d_in, const int* in_sizes, int n_in,
                              void* d_out, int out_size, void* d_ws, size_t ws_size,
                              hipStream_t stream) {
    (void)in_sizes; (void)n_in; (void)out_size; (void)ws_size;
    const float* x = (const float*)d_in[0];       // [8192][4096] f32
    const float* w = (const float*)d_in[1];       // [64][4096] f32
    float* out = (float*)d_out;                   // probs [T][E] then map [T][E]

    float* wT = (float*)d_ws;                                     // 1 MB
    float* part = (float*)((char*)d_ws + (size_t)(1 << 20));      // 16 MB

    transpose_w_kernel<<<HIDDEN / 64, 256, 0, stream>>>(w, wT);
    logits_partial_kernel<<<(TOKENS / 64) * SPLIT, 256, 0, stream>>>(x, wT, part);
    reduce_topk_kernel<<<TOKENS / 4, 256, 0, stream>>>(part, out);
}